// Round 11
// baseline (255.238 us; speedup 1.0000x reference)
//
#include <hip/hip_runtime.h>
#include <hip/hip_bf16.h>

// Problem constants: N=20000 nodes, K=32 nbrs, C=128, H=256
#define NN    20000
#define KNN   32
#define CIN   128
#define HD    256
#define EE    (NN * KNN)        // 640000 edges
#define NT    20                // nodes per ec_main block (1 node per tile)
#define NBLK  (NN / NT)         // 1000 blocks
#define PZB   (NN / 32)         // 625 pz blocks

typedef __bf16 bf16x8_t __attribute__((ext_vector_type(8)));
typedef __bf16 bf16x4_t __attribute__((ext_vector_type(4)));
typedef float  f32x4_t  __attribute__((ext_vector_type(4)));

// Weight prep (tiny, 256 blocks): w1g = frag-ordered W1' = [W1a-W1b ; W1b]
//   w1g[((kt*4+qr)*256+n)*8+j] = W1'[k=kt*32+qr*8+j][n]
// w2t[n*256+k] = bf16(W2[k][n]).
// Must stay a separate kernel: ec_pz READS w1g — same-launch write would race.
__global__ void ec_wprep(const float* __restrict__ W1, const float* __restrict__ W2,
                         __bf16* __restrict__ w1g, __bf16* __restrict__ w2t) {
    int idx = blockIdx.x * 256 + threadIdx.x;     // 0..65535
    int k = idx >> 8, n = idx & 255;
    float v = (k < CIN) ? (W1[k * 256 + n] - W1[(k + CIN) * 256 + n])
                        : W1[k * 256 + n];
    int kt = k >> 5, qr = (k >> 3) & 3, j = k & 7;
    w1g[(size_t)((kt * 4 + qr) * 256 + n) * 8 + j] = (__bf16)v;
    w2t[n * 256 + k] = (__bf16)W2[k * 256 + n];
}

// Per-node precompute of both GEMM1 halves (senders repeat, so the 42 GF
// edge-GEMM1 collapses to 2.6 GF of node-GEMM):
//   Pq[n][f] = sum_k X[n][k]*(W1a-W1b)[k][f] + b1[f]   (fp32)
//   Zq[n][f] = sum_k X[n][k]*W1b[k][f]                 (bf16)
// Zero-LDS (round-10, kept): MFMA C-layout stores are already coalesced.
__global__ __launch_bounds__(512, 1) void ec_pz(
    const float* __restrict__ nf, const __bf16* __restrict__ w1g,
    const float* __restrict__ b1, float* __restrict__ Pq, __bf16* __restrict__ Zq)
{
    const int bid  = blockIdx.x;
    const int lane = threadIdx.x & 63;
    const int wave = threadIdx.x >> 6;
    const int qrow = lane >> 4;
    const int lcol = lane & 15;
    const int fsl  = wave * 32;

    // node features for this block's 32 nodes (lane-col = node), fp32 -> bf16
    bf16x8_t xv[2][4];
#pragma unroll
    for (int ni = 0; ni < 2; ++ni) {
        const float* row = nf + (size_t)(bid * 32 + ni * 16 + lcol) * CIN;
#pragma unroll
        for (int c = 0; c < 4; ++c) {
            f32x4_t a = *(const f32x4_t*)(row + c * 32 + qrow * 8);
            f32x4_t b = *(const f32x4_t*)(row + c * 32 + qrow * 8 + 4);
            bf16x8_t x;
#pragma unroll
            for (int j = 0; j < 4; ++j) { x[j] = (__bf16)a[j]; x[j + 4] = (__bf16)b[j]; }
            xv[ni][c] = x;
        }
    }

    float4 bias1[2];
#pragma unroll
    for (int mi = 0; mi < 2; ++mi)
        bias1[mi] = *(const float4*)(b1 + fsl + mi * 16 + qrow * 4);

    // ---- P half (w1g chunks 0..15), +b1, direct C-layout store ----
    {
        f32x4_t ay[2][2];
#pragma unroll
        for (int mi = 0; mi < 2; ++mi)
#pragma unroll
            for (int ni = 0; ni < 2; ++ni)
                ay[mi][ni] = (f32x4_t){0.f, 0.f, 0.f, 0.f};
#pragma unroll
        for (int kt = 0; kt < 4; ++kt) {
            bf16x8_t wy[2];
#pragma unroll
            for (int mi = 0; mi < 2; ++mi)
                wy[mi] = *(const bf16x8_t*)(w1g +
                    (size_t)((kt * 4 + qrow) * 256 + fsl + mi * 16 + lcol) * 8);
#pragma unroll
            for (int mi = 0; mi < 2; ++mi)
#pragma unroll
                for (int ni = 0; ni < 2; ++ni)
                    ay[mi][ni] = __builtin_amdgcn_mfma_f32_16x16x32_bf16(
                        wy[mi], xv[ni][kt], ay[mi][ni], 0, 0, 0);
        }
#pragma unroll
        for (int mi = 0; mi < 2; ++mi)
#pragma unroll
            for (int ni = 0; ni < 2; ++ni) {
                f32x4_t v = ay[mi][ni];
                v[0] += bias1[mi].x; v[1] += bias1[mi].y;
                v[2] += bias1[mi].z; v[3] += bias1[mi].w;
                *(f32x4_t*)(Pq + (size_t)(bid * 32 + ni * 16 + lcol) * 256
                               + fsl + mi * 16 + qrow * 4) = v;
            }
    }

    // ---- Z half (w1g chunks 16..31), no bias, direct bf16 store ----
    {
        f32x4_t az[2][2];
#pragma unroll
        for (int mi = 0; mi < 2; ++mi)
#pragma unroll
            for (int ni = 0; ni < 2; ++ni)
                az[mi][ni] = (f32x4_t){0.f, 0.f, 0.f, 0.f};
#pragma unroll
        for (int kt = 0; kt < 4; ++kt) {
            bf16x8_t wy[2];
#pragma unroll
            for (int mi = 0; mi < 2; ++mi)
                wy[mi] = *(const bf16x8_t*)(w1g +
                    (size_t)((16 + kt * 4 + qrow) * 256 + fsl + mi * 16 + lcol) * 8);
#pragma unroll
            for (int mi = 0; mi < 2; ++mi)
#pragma unroll
                for (int ni = 0; ni < 2; ++ni)
                    az[mi][ni] = __builtin_amdgcn_mfma_f32_16x16x32_bf16(
                        wy[mi], xv[ni][kt], az[mi][ni], 0, 0, 0);
        }
#pragma unroll
        for (int mi = 0; mi < 2; ++mi)
#pragma unroll
            for (int ni = 0; ni < 2; ++ni) {
                f32x4_t v = az[mi][ni];
                bf16x4_t b = { (__bf16)v[0], (__bf16)v[1], (__bf16)v[2], (__bf16)v[3] };
                *(bf16x4_t*)(Zq + (size_t)(bid * 32 + ni * 16 + lcol) * 256
                                + fsl + mi * 16 + qrow * 4) = b;
            }
    }
}

// One tile (round-11): GEMM2(t) reading Hr, H(t+1)-assemble fused into
// kt=4..7 consuming zfU (gathered ONE FULL TILE earlier -> ~4000 cyc cover
// for random-gather L2/L3 misses), while this tile issues gather Z(t+2)
// into zfI. Epilogue back in-tile (round-10's deferred variant regressed).
__device__ __forceinline__ void tile_body(
    const int tt, const __bf16* __restrict__ Hr, __bf16* __restrict__ Hw,
    bf16x8_t (&zfU)[4], bf16x8_t (&zfI)[4],
    const float* __restrict__ lP, const __bf16* __restrict__ Zq,
    const int* __restrict__ senders, float* __restrict__ out,
    const bf16x8_t (&w2f)[8][4], const float (&bias2)[4],
    int& sn, const int n0, const int qrow, const int lcol,
    const int e5, const int fb, const int ktb, const int fsl)
{
    // ---- issue gather Z(tt+2) into zfI (consumed at tile tt+1) ----
    if (tt + 2 < NT) {
        const __bf16* zb = Zq + (size_t)sn * HD + fb;
#pragma unroll
        for (int c = 0; c < 4; ++c)
            zfI[c] = *(const bf16x8_t*)(zb + c * 8);
    }
    int sn2 = 0;
    if (tt + 3 < NT) sn2 = senders[(n0 + tt + 3) * KNN + e5];

    const bool pre = (tt + 1 < NT);
    const int na = pre ? tt + 1 : 0;
    const float* pfA = lP + na * 256 + fb;

    f32x4_t acc2[2][4];
#pragma unroll
    for (int mi = 0; mi < 2; ++mi)
#pragma unroll
        for (int ni = 0; ni < 4; ++ni)
            acc2[mi][ni] = (f32x4_t){0.f, 0.f, 0.f, 0.f};

    // ---- GEMM2 (K=256) with assemble chunks fused into kt=4..7 ----
#pragma unroll
    for (int kt = 0; kt < 8; ++kt) {
        bf16x8_t af[2];
#pragma unroll
        for (int mi = 0; mi < 2; ++mi)
            af[mi] = *(const bf16x8_t*)(Hr +
                (size_t)((kt * 4 + qrow) * 32 + mi * 16 + lcol) * 8);
#pragma unroll
        for (int mi = 0; mi < 2; ++mi)
#pragma unroll
            for (int ni = 0; ni < 4; ++ni)
                acc2[mi][ni] = __builtin_amdgcn_mfma_f32_16x16x32_bf16(
                    af[mi], w2f[kt][ni], acc2[mi][ni], 0, 0, 0);
        if (kt >= 4 && pre) {
            const int c = kt - 4;             // compile-time in unrolled loop
            f32x4_t p0 = *(const f32x4_t*)(pfA + c * 8);
            f32x4_t p1 = *(const f32x4_t*)(pfA + c * 8 + 4);
            bf16x8_t h;
#pragma unroll
            for (int j = 0; j < 4; ++j) {
                h[j]     = (__bf16)fmaxf(p0[j] + (float)zfU[c][j],     0.f);
                h[j + 4] = (__bf16)fmaxf(p1[j] + (float)zfU[c][j + 4], 0.f);
            }
            *(bf16x8_t*)(Hw + (size_t)((ktb * 4 + c) * 32 + e5) * 8) = h;
        }
    }

    // ---- epilogue: max over the node's 32 edges, +b2, store ----
#pragma unroll
    for (int ni = 0; ni < 4; ++ni) {
        float mx = -3.402823466e38f;
#pragma unroll
        for (int mi = 0; mi < 2; ++mi)
#pragma unroll
            for (int r = 0; r < 4; ++r)
                mx = fmaxf(mx, acc2[mi][ni][r]);
        mx = fmaxf(mx, __shfl_xor(mx, 16, 64));
        mx = fmaxf(mx, __shfl_xor(mx, 32, 64));
        if (qrow == 0)
            out[(size_t)(n0 + tt) * HD + fsl + ni * 16 + lcol] = mx + bias2[ni];
    }
    sn = sn2;
    __syncthreads();   // publishes Hw for tile tt+1
    // hazards: Hw's previous readers (GEMM2(tt-1)) finished before
    // barrier(tt-1); this body runs after it. Hw's new readers (GEMM2(tt+1))
    // run after this barrier. zfU/zfI are registers (no LDS hazard).
}

// Main (round-11 = round-9 + distance-2 gather prefetch; deferred-epi
// reverted — measured −5 µs). 256 thr / 4 waves; wave w owns output-feature
// slice w*64 (w2f = 128 AGPR) and assembles slice w*64 of H.
// LDS 52 KB -> 2 blocks/CU at 2 waves/SIMD (≈132 arch + 128 AGPR, no spill).
__global__ __launch_bounds__(256, 1) void ec_main(
    const __bf16* __restrict__ Zq,       // [NN][HD] bf16
    const int*   __restrict__ senders,   // [EE]
    const float* __restrict__ Pq,        // [NN][HD] fp32 (b1 folded in)
    const __bf16* __restrict__ w2t,      // [256 n][256 k]
    const float* __restrict__ b2,
    float* __restrict__ out)             // [NN][HD] fp32
{
    __shared__ __attribute__((aligned(16))) __bf16 ldsH0[8192];     // 16 KB H even
    __shared__ __attribute__((aligned(16))) __bf16 ldsH1[8192];     // 16 KB H odd
    __shared__ __attribute__((aligned(16))) float  ldsP[NT * 256];  // 20 KB fp32 P'

    const int tid  = threadIdx.x;
    const int lane = tid & 63;
    const int wave = tid >> 6;           // 0..3
    const int qrow = lane >> 4;
    const int lcol = lane & 15;
    const int blk  = blockIdx.x;
    const int fsl  = wave * 64;          // this wave's feature slice (assemble + GEMM2)
    const int e5   = lane & 31;          // edge id for gather/senders
    const int half = lane >> 5;          // feature half within slice (assemble)
    const int fb   = fsl + half * 32;    // assemble feature base (32-aligned)
    const int ktb  = fb >> 5;            // frag kt for assemble writes
    const int n0   = blk * NT;

    // ---- cooperative P' load: NT rows x 256 fp32 ----
    {
        const float4* src = (const float4*)(Pq + (size_t)n0 * 256);
        float4* dst = (float4*)ldsP;
#pragma unroll
        for (int i = 0; i < 5; ++i)
            dst[tid + i * 256] = src[tid + i * 256];
    }

    // ---- sender indices for tiles 0,1,2; gathers Z(0) and Z(1) ----
    int s0 = senders[(n0 + 0) * KNN + e5];
    int s1 = senders[(n0 + 1) * KNN + e5];
    int sn = senders[(n0 + 2) * KNN + e5];   // rolled: tile 0 issues Z(2)

    bf16x8_t zf0[4];
    {
        const __bf16* zb = Zq + (size_t)s0 * HD + fb;
#pragma unroll
        for (int c = 0; c < 4; ++c)
            zf0[c] = *(const bf16x8_t*)(zb + c * 8);
    }
    bf16x8_t zfA[4], zfB[4];
    {
        const __bf16* zb = Zq + (size_t)s1 * HD + fb;
#pragma unroll
        for (int c = 0; c < 4; ++c)
            zfA[c] = *(const bf16x8_t*)(zb + c * 8);
    }

    // ---- register-resident W2 slice (64 features): 128 regs ----
    bf16x8_t w2f[8][4];
#pragma unroll
    for (int kt = 0; kt < 8; ++kt)
#pragma unroll
        for (int ni = 0; ni < 4; ++ni)
            w2f[kt][ni] = *(const bf16x8_t*)(w2t + (size_t)(fsl + ni * 16 + lcol) * 256
                                                 + kt * 32 + qrow * 8);
    float bias2[4];
#pragma unroll
    for (int ni = 0; ni < 4; ++ni)
        bias2[ni] = b2[fsl + ni * 16 + lcol];

    __syncthreads();   // ldsP ready

    // ---- assemble H(0) -> ldsH0: h = relu(P'[node0] + Z(0)) ----
    {
        const float* pf = ldsP + 0 * 256 + fb;
#pragma unroll
        for (int c = 0; c < 4; ++c) {
            f32x4_t p0 = *(const f32x4_t*)(pf + c * 8);
            f32x4_t p1 = *(const f32x4_t*)(pf + c * 8 + 4);
            bf16x8_t h;
#pragma unroll
            for (int j = 0; j < 4; ++j) {
                h[j]     = (__bf16)fmaxf(p0[j] + (float)zf0[c][j],     0.f);
                h[j + 4] = (__bf16)fmaxf(p1[j] + (float)zf0[c][j + 4], 0.f);
            }
            *(bf16x8_t*)(ldsH0 + (size_t)((ktb * 4 + c) * 32 + e5) * 8) = h;
        }
    }
    __syncthreads();   // ldsH0 published

#pragma unroll 1
    for (int tp = 0; tp < NT; tp += 2) {
        // even tile: consume zfA (= Z(tp+1)), issue Z(tp+2) into zfB
        tile_body(tp,     ldsH0, ldsH1, zfA, zfB, ldsP, Zq, senders, out,
                  w2f, bias2, sn, n0, qrow, lcol, e5, fb, ktb, fsl);
        // odd tile: consume zfB (= Z(tp+2)), issue Z(tp+3) into zfA
        tile_body(tp + 1, ldsH1, ldsH0, zfB, zfA, ldsP, Zq, senders, out,
                  w2f, bias2, sn, n0, qrow, lcol, e5, fb, ktb, fsl);
    }
}

extern "C" void kernel_launch(void* const* d_in, const int* in_sizes, int n_in,
                              void* d_out, int out_size, void* d_ws, size_t ws_size,
                              hipStream_t stream) {
    const float* nf      = (const float*)d_in[0];
    const int*   senders = (const int*)d_in[1];
    // d_in[2] = receivers: implicit (repeat(arange(N), K)), unused
    const float* W1 = (const float*)d_in[3];
    const float* b1 = (const float*)d_in[4];
    const float* W2 = (const float*)d_in[5];
    const float* b2 = (const float*)d_in[6];

    __bf16* w1g = (__bf16*)d_ws;                 // 128 KB frag-ordered W1'
    __bf16* w2t = w1g + 256 * 256;               // 128 KB [n][k] bf16 W2^T
    __bf16* Zq  = w2t + 256 * 256;               // 10.24 MB bf16 Z = X*W1b
    float*  Pq  = (float*)(Zq + (size_t)NN * HD);// 20.48 MB fp32 P' = X*(W1a-W1b)+b1

    ec_wprep<<<256, 256, 0, stream>>>(W1, W2, w1g, w2t);
    ec_pz<<<PZB, 512, 0, stream>>>(nf, w1g, b1, Pq, Zq);
    ec_main<<<NBLK, 256, 0, stream>>>(Zq, senders, Pq, w2t, b2, (float*)d_out);
}

// Round 12
// 201.028 us; speedup vs baseline: 1.2697x; 1.2697x over previous
//
#include <hip/hip_runtime.h>
#include <hip/hip_bf16.h>

// Problem constants: N=20000 nodes, K=32 nbrs, C=128, H=256
#define NN    20000
#define KNN   32
#define CIN   128
#define HD    256
#define EE    (NN * KNN)        // 640000 edges
#define NT    20                // nodes per ec_main block (1 node per tile)
#define NBLK  (NN / NT)         // 1000 blocks
#define PZB   (NN / 32)         // 625 pz blocks

typedef __bf16 bf16x8_t __attribute__((ext_vector_type(8)));
typedef __bf16 bf16x4_t __attribute__((ext_vector_type(4)));
typedef float  f32x4_t  __attribute__((ext_vector_type(4)));

// LDS-only barrier: s_waitcnt lgkmcnt(0) + s_barrier, WITHOUT the vmcnt(0)
// drain __syncthreads() emits. Our loop barrier only protects ldsH/ldsP
// (ds ops -> lgkmcnt); global gathers may stay in flight across it, which
// is what gives the Z-prefetch its cover. "memory" clobber pins ordering.
__device__ __forceinline__ void barrier_lgkm() {
    asm volatile("s_waitcnt lgkmcnt(0)\n\ts_barrier" ::: "memory");
}

// Weight prep (tiny, 256 blocks): w1g = frag-ordered W1' = [W1a-W1b ; W1b]
//   w1g[((kt*4+qr)*256+n)*8+j] = W1'[k=kt*32+qr*8+j][n]
// w2t[n*256+k] = bf16(W2[k][n]).
// Must stay a separate kernel: ec_pz READS w1g — same-launch write would race.
__global__ void ec_wprep(const float* __restrict__ W1, const float* __restrict__ W2,
                         __bf16* __restrict__ w1g, __bf16* __restrict__ w2t) {
    int idx = blockIdx.x * 256 + threadIdx.x;     // 0..65535
    int k = idx >> 8, n = idx & 255;
    float v = (k < CIN) ? (W1[k * 256 + n] - W1[(k + CIN) * 256 + n])
                        : W1[k * 256 + n];
    int kt = k >> 5, qr = (k >> 3) & 3, j = k & 7;
    w1g[(size_t)((kt * 4 + qr) * 256 + n) * 8 + j] = (__bf16)v;
    w2t[n * 256 + k] = (__bf16)W2[k * 256 + n];
}

// Per-node precompute of both GEMM1 halves (senders repeat, so the 42 GF
// edge-GEMM1 collapses to 2.6 GF of node-GEMM):
//   Pq[n][f] = sum_k X[n][k]*(W1a-W1b)[k][f] + b1[f]   (fp32)
//   Zq[n][f] = sum_k X[n][k]*W1b[k][f]                 (bf16)
// Zero-LDS (round-10, kept): MFMA C-layout stores are already coalesced.
__global__ __launch_bounds__(512, 1) void ec_pz(
    const float* __restrict__ nf, const __bf16* __restrict__ w1g,
    const float* __restrict__ b1, float* __restrict__ Pq, __bf16* __restrict__ Zq)
{
    const int bid  = blockIdx.x;
    const int lane = threadIdx.x & 63;
    const int wave = threadIdx.x >> 6;
    const int qrow = lane >> 4;
    const int lcol = lane & 15;
    const int fsl  = wave * 32;

    // node features for this block's 32 nodes (lane-col = node), fp32 -> bf16
    bf16x8_t xv[2][4];
#pragma unroll
    for (int ni = 0; ni < 2; ++ni) {
        const float* row = nf + (size_t)(bid * 32 + ni * 16 + lcol) * CIN;
#pragma unroll
        for (int c = 0; c < 4; ++c) {
            f32x4_t a = *(const f32x4_t*)(row + c * 32 + qrow * 8);
            f32x4_t b = *(const f32x4_t*)(row + c * 32 + qrow * 8 + 4);
            bf16x8_t x;
#pragma unroll
            for (int j = 0; j < 4; ++j) { x[j] = (__bf16)a[j]; x[j + 4] = (__bf16)b[j]; }
            xv[ni][c] = x;
        }
    }

    float4 bias1[2];
#pragma unroll
    for (int mi = 0; mi < 2; ++mi)
        bias1[mi] = *(const float4*)(b1 + fsl + mi * 16 + qrow * 4);

    // ---- P half (w1g chunks 0..15), +b1, direct C-layout store ----
    {
        f32x4_t ay[2][2];
#pragma unroll
        for (int mi = 0; mi < 2; ++mi)
#pragma unroll
            for (int ni = 0; ni < 2; ++ni)
                ay[mi][ni] = (f32x4_t){0.f, 0.f, 0.f, 0.f};
#pragma unroll
        for (int kt = 0; kt < 4; ++kt) {
            bf16x8_t wy[2];
#pragma unroll
            for (int mi = 0; mi < 2; ++mi)
                wy[mi] = *(const bf16x8_t*)(w1g +
                    (size_t)((kt * 4 + qrow) * 256 + fsl + mi * 16 + lcol) * 8);
#pragma unroll
            for (int mi = 0; mi < 2; ++mi)
#pragma unroll
                for (int ni = 0; ni < 2; ++ni)
                    ay[mi][ni] = __builtin_amdgcn_mfma_f32_16x16x32_bf16(
                        wy[mi], xv[ni][kt], ay[mi][ni], 0, 0, 0);
        }
#pragma unroll
        for (int mi = 0; mi < 2; ++mi)
#pragma unroll
            for (int ni = 0; ni < 2; ++ni) {
                f32x4_t v = ay[mi][ni];
                v[0] += bias1[mi].x; v[1] += bias1[mi].y;
                v[2] += bias1[mi].z; v[3] += bias1[mi].w;
                *(f32x4_t*)(Pq + (size_t)(bid * 32 + ni * 16 + lcol) * 256
                               + fsl + mi * 16 + qrow * 4) = v;
            }
    }

    // ---- Z half (w1g chunks 16..31), no bias, direct bf16 store ----
    {
        f32x4_t az[2][2];
#pragma unroll
        for (int mi = 0; mi < 2; ++mi)
#pragma unroll
            for (int ni = 0; ni < 2; ++ni)
                az[mi][ni] = (f32x4_t){0.f, 0.f, 0.f, 0.f};
#pragma unroll
        for (int kt = 0; kt < 4; ++kt) {
            bf16x8_t wy[2];
#pragma unroll
            for (int mi = 0; mi < 2; ++mi)
                wy[mi] = *(const bf16x8_t*)(w1g +
                    (size_t)((16 + kt * 4 + qrow) * 256 + fsl + mi * 16 + lcol) * 8);
#pragma unroll
            for (int mi = 0; mi < 2; ++mi)
#pragma unroll
                for (int ni = 0; ni < 2; ++ni)
                    az[mi][ni] = __builtin_amdgcn_mfma_f32_16x16x32_bf16(
                        wy[mi], xv[ni][kt], az[mi][ni], 0, 0, 0);
        }
#pragma unroll
        for (int mi = 0; mi < 2; ++mi)
#pragma unroll
            for (int ni = 0; ni < 2; ++ni) {
                f32x4_t v = az[mi][ni];
                bf16x4_t b = { (__bf16)v[0], (__bf16)v[1], (__bf16)v[2], (__bf16)v[3] };
                *(bf16x4_t*)(Zq + (size_t)(bid * 32 + ni * 16 + lcol) * 256
                                + fsl + mi * 16 + qrow * 4) = b;
            }
    }
}

// One tile (round-12): identical compute to round 9, but (a) the Z(tt+2)
// gather is issued AFTER this tile's kt-loop (zf just got consumed at
// kt=4..7) and stays IN FLIGHT across the lgkm-only barrier — cover grows
// from ~640 cyc to epi+barrier+next-tile-kt0..3 (~1500+ cyc), enough for
// L3 misses on the random gather; (b) barrier is lgkmcnt-only.
// Register-neutral vs round 9 (same single zf buffer; in-order issue makes
// consume-then-reissue on the same regs safe).
__device__ __forceinline__ void tile_body(
    const int tt, const __bf16* __restrict__ Hr, __bf16* __restrict__ Hw,
    bf16x8_t (&zf)[4],
    const float* __restrict__ lP, const __bf16* __restrict__ Zq,
    const int* __restrict__ senders, float* __restrict__ out,
    const bf16x8_t (&w2f)[8][4], const float (&bias2)[4],
    int& sn, const int n0, const int qrow, const int lcol,
    const int e5, const int fb, const int ktb, const int fsl)
{
    const bool pre = (tt + 1 < NT);
    const int na = pre ? tt + 1 : 0;
    const float* pfA = lP + na * 256 + fb;

    f32x4_t acc2[2][4];
#pragma unroll
    for (int mi = 0; mi < 2; ++mi)
#pragma unroll
        for (int ni = 0; ni < 4; ++ni)
            acc2[mi][ni] = (f32x4_t){0.f, 0.f, 0.f, 0.f};

    // ---- GEMM2 (K=256) with assemble chunks fused into kt=4..7 ----
#pragma unroll
    for (int kt = 0; kt < 8; ++kt) {
        bf16x8_t af[2];
#pragma unroll
        for (int mi = 0; mi < 2; ++mi)
            af[mi] = *(const bf16x8_t*)(Hr +
                (size_t)((kt * 4 + qrow) * 32 + mi * 16 + lcol) * 8);
#pragma unroll
        for (int mi = 0; mi < 2; ++mi)
#pragma unroll
            for (int ni = 0; ni < 4; ++ni)
                acc2[mi][ni] = __builtin_amdgcn_mfma_f32_16x16x32_bf16(
                    af[mi], w2f[kt][ni], acc2[mi][ni], 0, 0, 0);
        if (kt >= 4 && pre) {
            const int c = kt - 4;             // compile-time in unrolled loop
            f32x4_t p0 = *(const f32x4_t*)(pfA + c * 8);
            f32x4_t p1 = *(const f32x4_t*)(pfA + c * 8 + 4);
            bf16x8_t h;
#pragma unroll
            for (int j = 0; j < 4; ++j) {
                h[j]     = (__bf16)fmaxf(p0[j] + (float)zf[c][j],     0.f);
                h[j + 4] = (__bf16)fmaxf(p1[j] + (float)zf[c][j + 4], 0.f);
            }
            *(bf16x8_t*)(Hw + (size_t)((ktb * 4 + c) * 32 + e5) * 8) = h;
        }
    }

    // ---- issue gather Z(tt+2) into zf (consumed at tile tt+1's kt>=4);
    //      crosses the lgkm-only barrier still in flight ----
    if (tt + 2 < NT) {
        const __bf16* zb = Zq + (size_t)sn * HD + fb;
#pragma unroll
        for (int c = 0; c < 4; ++c)
            zf[c] = *(const bf16x8_t*)(zb + c * 8);
    }
    if (tt + 3 < NT) sn = senders[(n0 + tt + 3) * KNN + e5];

    // ---- epilogue: max over the node's 32 edges, +b2, store ----
#pragma unroll
    for (int ni = 0; ni < 4; ++ni) {
        float mx = -3.402823466e38f;
#pragma unroll
        for (int mi = 0; mi < 2; ++mi)
#pragma unroll
            for (int r = 0; r < 4; ++r)
                mx = fmaxf(mx, acc2[mi][ni][r]);
        mx = fmaxf(mx, __shfl_xor(mx, 16, 64));
        mx = fmaxf(mx, __shfl_xor(mx, 32, 64));
        if (qrow == 0)
            out[(size_t)(n0 + tt) * HD + fsl + ni * 16 + lcol] = mx + bias2[ni];
    }

    barrier_lgkm();   // publishes Hw (ds ops drained); Z-gather stays in flight
    // hazards: Hw's previous readers (GEMM2(tt-1)) completed their ds_reads
    // before barrier(tt-1) (lgkmcnt(0) drains reads too); this body's writes
    // run after it. Hw's new readers (GEMM2(tt+1)) run after this barrier.
    // zf is per-wave registers — no cross-wave hazard; in-order issue means
    // the reissue cannot overwrite before the kt>=4 consumers executed.
}

// Main (round-12 = round-9 + lgkm-only barrier + cross-barrier Z prefetch).
// 256 thr / 4 waves; wave w owns output-feature slice w*64 (w2f = 128 AGPR)
// and assembles slice w*64 of H. LDS 52 KB -> 2 blocks/CU at 2 waves/SIMD
// (~116 arch + 128 AGPR, no spill — the ≤124-arch budget is a hard guard).
__global__ __launch_bounds__(256, 1) void ec_main(
    const __bf16* __restrict__ Zq,       // [NN][HD] bf16
    const int*   __restrict__ senders,   // [EE]
    const float* __restrict__ Pq,        // [NN][HD] fp32 (b1 folded in)
    const __bf16* __restrict__ w2t,      // [256 n][256 k]
    const float* __restrict__ b2,
    float* __restrict__ out)             // [NN][HD] fp32
{
    __shared__ __attribute__((aligned(16))) __bf16 ldsH0[8192];     // 16 KB H even
    __shared__ __attribute__((aligned(16))) __bf16 ldsH1[8192];     // 16 KB H odd
    __shared__ __attribute__((aligned(16))) float  ldsP[NT * 256];  // 20 KB fp32 P'

    const int tid  = threadIdx.x;
    const int lane = tid & 63;
    const int wave = tid >> 6;           // 0..3
    const int qrow = lane >> 4;
    const int lcol = lane & 15;
    const int blk  = blockIdx.x;
    const int fsl  = wave * 64;          // this wave's feature slice (assemble + GEMM2)
    const int e5   = lane & 31;          // edge id for gather/senders
    const int half = lane >> 5;          // feature half within slice (assemble)
    const int fb   = fsl + half * 32;    // assemble feature base (32-aligned)
    const int ktb  = fb >> 5;            // frag kt for assemble writes
    const int n0   = blk * NT;

    // ---- cooperative P' load: NT rows x 256 fp32 ----
    {
        const float4* src = (const float4*)(Pq + (size_t)n0 * 256);
        float4* dst = (float4*)ldsP;
#pragma unroll
        for (int i = 0; i < 5; ++i)
            dst[tid + i * 256] = src[tid + i * 256];
    }

    // ---- sender indices for tiles 0,1,2; gather Z(0) ----
    int s0  = senders[(n0 + 0) * KNN + e5];
    int sn1 = senders[(n0 + 1) * KNN + e5];
    int sn  = senders[(n0 + 2) * KNN + e5];

    bf16x8_t zf[4];
    {
        const __bf16* zb = Zq + (size_t)s0 * HD + fb;
#pragma unroll
        for (int c = 0; c < 4; ++c)
            zf[c] = *(const bf16x8_t*)(zb + c * 8);
    }

    // ---- register-resident W2 slice (64 features): 128 regs ----
    bf16x8_t w2f[8][4];
#pragma unroll
    for (int kt = 0; kt < 8; ++kt)
#pragma unroll
        for (int ni = 0; ni < 4; ++ni)
            w2f[kt][ni] = *(const bf16x8_t*)(w2t + (size_t)(fsl + ni * 16 + lcol) * 256
                                                 + kt * 32 + qrow * 8);
    float bias2[4];
#pragma unroll
    for (int ni = 0; ni < 4; ++ni)
        bias2[ni] = b2[fsl + ni * 16 + lcol];

    __syncthreads();   // ldsP ready (full drain fine here: Z(0) is needed now)

    // ---- assemble H(0) -> ldsH0: h = relu(P'[node0] + Z(0)) ----
    {
        const float* pf = ldsP + 0 * 256 + fb;
#pragma unroll
        for (int c = 0; c < 4; ++c) {
            f32x4_t p0 = *(const f32x4_t*)(pf + c * 8);
            f32x4_t p1 = *(const f32x4_t*)(pf + c * 8 + 4);
            bf16x8_t h;
#pragma unroll
            for (int j = 0; j < 4; ++j) {
                h[j]     = (__bf16)fmaxf(p0[j] + (float)zf[c][j],     0.f);
                h[j + 4] = (__bf16)fmaxf(p1[j] + (float)zf[c][j + 4], 0.f);
            }
            *(bf16x8_t*)(ldsH0 + (size_t)((ktb * 4 + c) * 32 + e5) * 8) = h;
        }
    }

    // ---- issue gather Z(1) (consumed at tile 0's kt>=4); crosses barrier ----
    {
        const __bf16* zb = Zq + (size_t)sn1 * HD + fb;
#pragma unroll
        for (int c = 0; c < 4; ++c)
            zf[c] = *(const bf16x8_t*)(zb + c * 8);
    }

    barrier_lgkm();    // ldsH0 published; Z(1) stays in flight

#pragma unroll 1
    for (int tp = 0; tp < NT; tp += 2) {
        tile_body(tp,     ldsH0, ldsH1, zf, ldsP, Zq, senders, out,
                  w2f, bias2, sn, n0, qrow, lcol, e5, fb, ktb, fsl);
        tile_body(tp + 1, ldsH1, ldsH0, zf, ldsP, Zq, senders, out,
                  w2f, bias2, sn, n0, qrow, lcol, e5, fb, ktb, fsl);
    }
}

extern "C" void kernel_launch(void* const* d_in, const int* in_sizes, int n_in,
                              void* d_out, int out_size, void* d_ws, size_t ws_size,
                              hipStream_t stream) {
    const float* nf      = (const float*)d_in[0];
    const int*   senders = (const int*)d_in[1];
    // d_in[2] = receivers: implicit (repeat(arange(N), K)), unused
    const float* W1 = (const float*)d_in[3];
    const float* b1 = (const float*)d_in[4];
    const float* W2 = (const float*)d_in[5];
    const float* b2 = (const float*)d_in[6];

    __bf16* w1g = (__bf16*)d_ws;                 // 128 KB frag-ordered W1'
    __bf16* w2t = w1g + 256 * 256;               // 128 KB [n][k] bf16 W2^T
    __bf16* Zq  = w2t + 256 * 256;               // 10.24 MB bf16 Z = X*W1b
    float*  Pq  = (float*)(Zq + (size_t)NN * HD);// 20.48 MB fp32 P' = X*(W1a-W1b)+b1

    ec_wprep<<<256, 256, 0, stream>>>(W1, W2, w1g, w2t);
    ec_pz<<<PZB, 512, 0, stream>>>(nf, w1g, b1, Pq, Zq);
    ec_main<<<NBLK, 256, 0, stream>>>(Zq, senders, Pq, w2t, b2, (float*)d_out);
}